// Round 2
// baseline (210.386 us; speedup 1.0000x reference)
//
#include <hip/hip_runtime.h>

// B=8, C=256, N=2048, fp32 in/out.
// attn_b = (Ap_b x_b + cvec_b 1^T) / S
//   Ap_b = T1_b W3 + wvsx_b (x) u2 + bv (x) v2_b      (f16 hi/lo split MFMA)
//   T1_b = Wv G_b,  W3 = Wq^T Wk,  G_b = x_b x_b^T (symmetric)
//   u2 = Wk^T bq, w1 = Wq^T bk, s1 = bq.bk, sx_b = rowsum(x_b)
//   v2_b = W3^T sx_b + N u2;  s2_b = sx.w1 + N s1;  S = sum_b [v2.sx + N s2]
//   cvec_b = T1.w1 + wvsx*s1 + bv*s2    (computed inside ap stage)
//
// THIS ROUND: single fused kernel, 4 bulk-synchronous stages separated by
// software grid barriers. Rationale: round-0's substantial interior changes
// were a perfect null (152.8->154.3us) while per-kernel rooflines sum to
// ~30us -> the remaining time is per-dispatch overhead (launch + drain + L2
// writeback/inv per node) and/or fixed harness overhead. Unlike the old
// regressed mega-kernel (producer/consumer spin, <=50% utilization, per-poll
// L2 invalidation), here ALL 256 blocks work in EVERY stage and the barrier
// spins on a relaxed agent-scope (LLC-coherent, sc1) load with s_sleep
// backoff -- no cache invalidation per poll; one threadfence pair per
// barrier. 256 blocks @ 56KB LDS, launch_bounds(256,1) -> 1 block/CU
// guaranteed co-resident on 256 CUs -> no deadlock. Stage code is
// byte-identical to the 4-kernel version -> identical numerics.

typedef _Float16 half8 __attribute__((ext_vector_type(8)));
typedef _Float16 half4 __attribute__((ext_vector_type(4)));
typedef _Float16 half2v __attribute__((ext_vector_type(2)));
typedef float f4v __attribute__((ext_vector_type(4)));

#define GP  40   // LDS pitch (halves), A panels / gemmG (16B-aligned rows)
#define GPB 36   // gemmF B panel pitch: 18-dword row stride -> 2-way (free) banking

// One-shot grid barrier (cnt/flag zeroed by host-side memset before launch).
// Poll = relaxed agent-scope load (compiles to sc1 global_load: LLC-coherent,
// bypasses the non-coherent per-XCD L2, does NOT invalidate caches per poll).
// Release/acquire via explicit __threadfence around the arrive/depart.
__device__ __forceinline__ void gbar(unsigned* cnt, unsigned* flag, unsigned nblk) {
    __syncthreads();
    if (threadIdx.x == 0) {
        __threadfence();   // release: write back this block's stage outputs
        if (__hip_atomic_fetch_add(cnt, 1u, __ATOMIC_RELAXED, __HIP_MEMORY_SCOPE_AGENT) == nblk - 1u) {
            __hip_atomic_store(flag, 1u, __ATOMIC_RELAXED, __HIP_MEMORY_SCOPE_AGENT);
        } else {
            while (__hip_atomic_load(flag, __ATOMIC_RELAXED, __HIP_MEMORY_SCOPE_AGENT) == 0u)
                __builtin_amdgcn_s_sleep(2);
        }
        __threadfence();   // acquire: invalidate stale L1/L2 before reading peers' outputs
    }
    __syncthreads();
}

__launch_bounds__(256, 1)
__global__ void fused_kernel(const float* __restrict__ x, const float* __restrict__ Wq,
                             const float* __restrict__ bq, const float* __restrict__ Wk,
                             const float* __restrict__ bk, const float* __restrict__ Wv,
                             const float* __restrict__ bv, float* __restrict__ out,
                             float* __restrict__ T1, float* __restrict__ W3,
                             float* __restrict__ sxpart, float* __restrict__ wvsx,
                             float* __restrict__ v2, float* __restrict__ cvec,
                             float* __restrict__ s2, float* __restrict__ u2,
                             float* __restrict__ w1, float* __restrict__ s1,
                             float* __restrict__ S, float* __restrict__ Gpart,
                             _Float16* __restrict__ Aph, _Float16* __restrict__ Apl,
                             unsigned* __restrict__ bar) {
    // 55808 B = max over stages (stage-4 carve: Ah 10240 | Al 10240 | Bh 9216 |
    // Bl 9216 | xt 16896). Stage 1 uses the first 40960 B.
    __shared__ __align__(16) char smem[55808];
    const int blk = blockIdx.x, t = threadIdx.x;
    const unsigned NBLK = 256;

    // ================= STAGE 1: gemmG splitK=8 (+rowsum) | W3 | u2/w1/s1 =================
    if (blk < 192) {
        _Float16* Ah = (_Float16*)smem;
        _Float16* Al = Ah + 128 * GP;
        _Float16* Bh = Al + 128 * GP;
        _Float16* Bl = Bh + 128 * GP;
        const int tileId = blk >> 6;           // 0..2
        const int y = blk & 63;                // 0..63
        const int b = y >> 3, ks = y & 7;
        const int r0 = (tileId == 2) ? 128 : 0;
        const int c0 = (tileId == 0) ? 0 : 128;
        const bool diag = (tileId != 1);
        const float* xb = x + (long)b * 524288;

        const int lane = t & 63, wave = t >> 6;
        const int wy = wave >> 1, wx = wave & 1;
        const int mIn = lane & 15, quad = lane >> 4;

        f4v acc[4][4] = {};
        const int aBase = (wy * 64 + mIn) * GP + quad * 8;
        const int bBase = (wx * 64 + mIn) * GP + quad * 8;
        const int srow = t >> 3;               // 0..31
        const int skq  = (t & 7) * 4;          // 0..28
        float rs[4] = {};                      // rowsum partials (diag only)

        float4 pa[4], pb[4];
        int kk = ks * 256;
        #pragma unroll
        for (int i = 0; i < 4; ++i) {
            pa[i] = *(const float4*)&xb[(long)(r0 + srow + i * 32) * 2048 + kk + skq];
            if (!diag) pb[i] = *(const float4*)&xb[(long)(c0 + srow + i * 32) * 2048 + kk + skq];
        }

        for (int kb = 0; kb < 8; ++kb) {
            if (kb) __syncthreads();
            #pragma unroll
            for (int i = 0; i < 4; ++i) {
                const int row = srow + i * 32;
                half4 hv, lv;
                hv[0] = (_Float16)pa[i].x; lv[0] = (_Float16)(pa[i].x - (float)hv[0]);
                hv[1] = (_Float16)pa[i].y; lv[1] = (_Float16)(pa[i].y - (float)hv[1]);
                hv[2] = (_Float16)pa[i].z; lv[2] = (_Float16)(pa[i].z - (float)hv[2]);
                hv[3] = (_Float16)pa[i].w; lv[3] = (_Float16)(pa[i].w - (float)hv[3]);
                *(half4*)&Ah[row * GP + skq] = hv;
                *(half4*)&Al[row * GP + skq] = lv;
                if (diag) {
                    rs[i] += pa[i].x + pa[i].y + pa[i].z + pa[i].w;
                } else {
                    half4 hb, lb;
                    hb[0] = (_Float16)pb[i].x; lb[0] = (_Float16)(pb[i].x - (float)hb[0]);
                    hb[1] = (_Float16)pb[i].y; lb[1] = (_Float16)(pb[i].y - (float)hb[1]);
                    hb[2] = (_Float16)pb[i].z; lb[2] = (_Float16)(pb[i].z - (float)hb[2]);
                    hb[3] = (_Float16)pb[i].w; lb[3] = (_Float16)(pb[i].w - (float)hb[3]);
                    *(half4*)&Bh[row * GP + skq] = hb;
                    *(half4*)&Bl[row * GP + skq] = lb;
                }
            }
            __syncthreads();
            kk += 32;
            if (kb < 7) {
                #pragma unroll
                for (int i = 0; i < 4; ++i) {
                    pa[i] = *(const float4*)&xb[(long)(r0 + srow + i * 32) * 2048 + kk + skq];
                    if (!diag) pb[i] = *(const float4*)&xb[(long)(c0 + srow + i * 32) * 2048 + kk + skq];
                }
            }
            const _Float16* BhP = diag ? Ah : Bh;
            const _Float16* BlP = diag ? Al : Bl;
            #pragma unroll
            for (int ph = 0; ph < 3; ++ph) {
                const _Float16* As = (ph == 2) ? Al : Ah;
                const _Float16* Bs = (ph == 1) ? BlP : BhP;
                half8 af[4], bf[4];
                #pragma unroll
                for (int i = 0; i < 4; ++i) {
                    af[i] = *(const half8*)&As[aBase + i * 16 * GP];
                    bf[i] = *(const half8*)&Bs[bBase + i * 16 * GP];
                }
                #pragma unroll
                for (int i = 0; i < 4; ++i)
                    #pragma unroll
                    for (int j = 0; j < 4; ++j)
                        acc[i][j] = __builtin_amdgcn_mfma_f32_16x16x32_f16(af[i], bf[j], acc[i][j], 0, 0, 0);
            }
        }

        if (diag) {
            #pragma unroll
            for (int i = 0; i < 4; ++i) {
                rs[i] += __shfl_xor(rs[i], 1);
                rs[i] += __shfl_xor(rs[i], 2);
                rs[i] += __shfl_xor(rs[i], 4);
            }
            if ((t & 7) == 0) {
                #pragma unroll
                for (int i = 0; i < 4; ++i)
                    sxpart[ks * 2048 + b * 256 + r0 + srow + i * 32] = rs[i];
            }
        }

        float* D = Gpart + ((long)(ks * 8 + b) << 16);
        #pragma unroll
        for (int i = 0; i < 4; ++i)
            #pragma unroll
            for (int j = 0; j < 4; ++j) {
                const int row = r0 + wy * 64 + i * 16 + quad * 4;
                const int col = c0 + wx * 64 + j * 16 + mIn;
                #pragma unroll
                for (int r = 0; r < 4; ++r)
                    D[(row + r) * 256 + col] = acc[i][j][r];
                if (tileId == 1)
                    *(float4*)&D[(long)col * 256 + row] =
                        make_float4(acc[i][j][0], acc[i][j][1], acc[i][j][2], acc[i][j][3]);
            }
    } else if (blk < 208) {
        float* ldsA = (float*)smem;
        float* ldsB = ldsA + 16 * 68;
        const int tile = blk - 192;
        const int r0 = (tile >> 2) * 64, j0 = (tile & 3) * 64;
        const int tx = t & 15, ty = t >> 4;
        float acc[4][4] = {};
        for (int kk = 0; kk < 256; kk += 16) {
            *(float4*)&ldsA[ty * 68 + tx * 4] = *(const float4*)&Wq[(long)(kk + ty) * 256 + r0 + tx * 4];
            *(float4*)&ldsB[ty * 68 + tx * 4] = *(const float4*)&Wk[(long)(kk + ty) * 256 + j0 + tx * 4];
            __syncthreads();
            #pragma unroll
            for (int k = 0; k < 16; ++k) {
                const float4 av4 = *(const float4*)&ldsA[k * 68 + ty * 4];
                const float4 bv4 = *(const float4*)&ldsB[k * 68 + tx * 4];
                const float ar[4] = {av4.x, av4.y, av4.z, av4.w};
                const float br[4] = {bv4.x, bv4.y, bv4.z, bv4.w};
                #pragma unroll
                for (int i = 0; i < 4; ++i)
                    #pragma unroll
                    for (int j = 0; j < 4; ++j)
                        acc[i][j] = fmaf(ar[i], br[j], acc[i][j]);
            }
            __syncthreads();
        }
        #pragma unroll
        for (int i = 0; i < 4; ++i)
            *(float4*)&W3[(long)(r0 + ty * 4 + i) * 256 + j0 + tx * 4] =
                make_float4(acc[i][0], acc[i][1], acc[i][2], acc[i][3]);
    } else if (blk == 208) {
        float* sbq = (float*)smem;
        float* sbk = sbq + 256;
        float* red = sbk + 256;
        if (t == 0) S[0] = 0.0f;
        sbq[t] = bq[t]; sbk[t] = bk[t];
        __syncthreads();
        float u = 0.0f, w = 0.0f;
        #pragma unroll 8
        for (int c = 0; c < 256; ++c) {
            u = fmaf(Wk[(long)c * 256 + t], sbq[c], u);   // coalesced columns
            w = fmaf(Wq[(long)c * 256 + t], sbk[c], w);
        }
        u2[t] = u; w1[t] = w;
        red[t] = sbq[t] * sbk[t]; __syncthreads();
        for (int h = 128; h > 0; h >>= 1) { if (t < h) red[t] += red[t + h]; __syncthreads(); }
        if (t == 0) s1[0] = red[0];
    }

    gbar(&bar[0], &bar[1], NBLK);

    // ================= STAGE 2: T1 = Wv G (32x64 tiles, all 256 blocks) =================
    {
        float* ldsA = (float*)smem;            // [32 k][34] transposed Wv panel
        float* ldsB = ldsA + 32 * 34;          // [32 k][68] reduced G panel
        const int r0 = (blk >> 5) * 32;        // 0..224
        const int g  = blk & 31;
        const int b  = g >> 2;
        const int j0 = (g & 3) * 64;
        const int tx = t & 15, ty = t >> 4;
        const int ar = t >> 3, ak4 = (t & 7) * 4;
        const float* Gb = Gpart + (long)b * 65536 + j0;
        float acc[2][4] = {};

        f4v pa, pg[2][8];
        pa = *(const f4v*)&Wv[(long)(r0 + ar) * 256 + ak4];
        #pragma unroll
        for (int s = 0; s < 2; ++s)
            #pragma unroll
            for (int ksl = 0; ksl < 8; ++ksl)
                pg[s][ksl] = *(const f4v*)&Gb[(long)ksl * 524288 + (long)(s * 16 + ty) * 256 + tx * 4];

        for (int c = 0; c < 8; ++c) {
            const int kk = c * 32;
            ldsA[(ak4 + 0) * 34 + ar] = pa[0];
            ldsA[(ak4 + 1) * 34 + ar] = pa[1];
            ldsA[(ak4 + 2) * 34 + ar] = pa[2];
            ldsA[(ak4 + 3) * 34 + ar] = pa[3];
            #pragma unroll
            for (int s = 0; s < 2; ++s) {
                f4v bs = pg[s][0];
                #pragma unroll
                for (int ksl = 1; ksl < 8; ++ksl) bs += pg[s][ksl];
                *(f4v*)&ldsB[(s * 16 + ty) * 68 + tx * 4] = bs;
            }
            __syncthreads();
            if (c < 7) {
                const int kn = kk + 32;
                pa = *(const f4v*)&Wv[(long)(r0 + ar) * 256 + kn + ak4];
                #pragma unroll
                for (int s = 0; s < 2; ++s)
                    #pragma unroll
                    for (int ksl = 0; ksl < 8; ++ksl)
                        pg[s][ksl] = *(const f4v*)&Gb[(long)ksl * 524288 + (long)(kn + s * 16 + ty) * 256 + tx * 4];
            }
            #pragma unroll
            for (int k = 0; k < 32; ++k) {
                const float2 av2 = *(const float2*)&ldsA[k * 34 + ty * 2];
                const float4 bv4 = *(const float4*)&ldsB[k * 68 + tx * 4];
                acc[0][0] = fmaf(av2.x, bv4.x, acc[0][0]);
                acc[0][1] = fmaf(av2.x, bv4.y, acc[0][1]);
                acc[0][2] = fmaf(av2.x, bv4.z, acc[0][2]);
                acc[0][3] = fmaf(av2.x, bv4.w, acc[0][3]);
                acc[1][0] = fmaf(av2.y, bv4.x, acc[1][0]);
                acc[1][1] = fmaf(av2.y, bv4.y, acc[1][1]);
                acc[1][2] = fmaf(av2.y, bv4.z, acc[1][2]);
                acc[1][3] = fmaf(av2.y, bv4.w, acc[1][3]);
            }
            __syncthreads();
        }
        float* D = T1 + (long)b * 65536;
        #pragma unroll
        for (int i = 0; i < 2; ++i)
            *(float4*)&D[(long)(r0 + ty * 2 + i) * 256 + j0 + tx * 4] =
                make_float4(acc[i][0], acc[i][1], acc[i][2], acc[i][3]);
    }
    // stage-2 small jobs (second duty for blocks 0..15; inputs are stage-1 outputs)
    if (blk < 8) {
        __syncthreads();
        float* ssx = (float*)smem;
        float* red = ssx + 256;
        const int b = blk, j = t;
        float sxv = 0.0f;
        #pragma unroll
        for (int ks = 0; ks < 8; ++ks) sxv += sxpart[ks * 2048 + b * 256 + j];
        ssx[j] = sxv;
        __syncthreads();
        float vr = 0.0f;
        #pragma unroll 8
        for (int c = 0; c < 256; ++c) vr = fmaf(W3[(long)c * 256 + j], ssx[c], vr); // coalesced
        const float v2j = vr + 2048.0f * u2[j];
        v2[b * 256 + j] = v2j;
        red[j] = v2j * sxv; __syncthreads();
        for (int h = 128; h > 0; h >>= 1) { if (j < h) red[j] += red[j + h]; __syncthreads(); }
        const float sd1 = red[0];
        __syncthreads();
        red[j] = sxv * w1[j]; __syncthreads();
        for (int h = 128; h > 0; h >>= 1) { if (j < h) red[j] += red[j + h]; __syncthreads(); }
        if (j == 0) {
            const float s2v = red[0] + 2048.0f * s1[0];
            s2[b] = s2v;
            atomicAdd(S, sd1 + 2048.0f * s2v);
        }
    } else if (blk < 16) {
        __syncthreads();
        float* wtile = (float*)smem;           // 32 x 256
        float* sxs = wtile + 8192;             // 2048
        const int r0w = (blk - 8) * 32;
        #pragma unroll
        for (int p = 0; p < 8; ++p) {
            const int f = t + p * 256;
            const int row = f >> 6, c4 = f & 63;
            *(float4*)&wtile[row * 256 + c4 * 4] = *(const float4*)&Wv[(long)(r0w + row) * 256 + c4 * 4];
        }
        #pragma unroll
        for (int p = 0; p < 8; ++p) {
            const int f = t + p * 256;
            float s = 0.0f;
            #pragma unroll
            for (int ks = 0; ks < 8; ++ks) s += sxpart[ks * 2048 + f];
            sxs[f] = s;
        }
        __syncthreads();
        const int r = t >> 3, q = t & 7;       // 32 rows x 8 k-groups
        float acc[8] = {};
        for (int ci = 0; ci < 32; ++ci) {
            const float wv = wtile[r * 256 + q * 32 + ci];
            #pragma unroll
            for (int b = 0; b < 8; ++b) acc[b] = fmaf(wv, sxs[b * 256 + q * 32 + ci], acc[b]);
        }
        #pragma unroll
        for (int b = 0; b < 8; ++b) {
            acc[b] += __shfl_xor(acc[b], 1);
            acc[b] += __shfl_xor(acc[b], 2);
            acc[b] += __shfl_xor(acc[b], 4);
        }
        if (q == 0) {
            #pragma unroll
            for (int b = 0; b < 8; ++b) wvsx[b * 256 + r0w + r] = acc[b];
        }
    }

    gbar(&bar[2], &bar[3], NBLK);

    // ================= STAGE 3: Ap = T1 W3 + wvsx(x)u2 + bv(x)v2 -> f16 hi/lo; cvec =================
    {
        float* ldsA = (float*)smem;            // [32 k][34] transposed T1 panel (4352 B)
        float* ldsB = (float*)(smem + 4352);   // [32 k][68] W3 panel (8704 B)
        float* sw1  = (float*)(smem + 13056);  // 256 floats
        const int b  = blk >> 5;
        const int r0 = ((blk >> 2) & 7) * 32, j0 = (blk & 3) * 64;
        const float* A = T1 + (long)b * 65536;
        const int tx = t & 15, ty = t >> 4;
        const int ar = t >> 3, ak4 = (t & 7) * 4;
        sw1[t] = w1[t];
        float acc[2][4] = {};
        float dot[2] = {};

        f4v pa, pb[2];
        pa = *(const f4v*)&A[(long)(r0 + ar) * 256 + ak4];
        pb[0] = *(const f4v*)&W3[(long)(ty) * 256 + j0 + tx * 4];
        pb[1] = *(const f4v*)&W3[(long)(16 + ty) * 256 + j0 + tx * 4];

        for (int c = 0; c < 8; ++c) {
            const int kk = c * 32;
            ldsA[(ak4 + 0) * 34 + ar] = pa[0];
            ldsA[(ak4 + 1) * 34 + ar] = pa[1];
            ldsA[(ak4 + 2) * 34 + ar] = pa[2];
            ldsA[(ak4 + 3) * 34 + ar] = pa[3];
            *(f4v*)&ldsB[ty * 68 + tx * 4] = pb[0];
            *(f4v*)&ldsB[(16 + ty) * 68 + tx * 4] = pb[1];
            __syncthreads();
            if (c < 7) {
                const int kn = kk + 32;
                pa = *(const f4v*)&A[(long)(r0 + ar) * 256 + kn + ak4];
                pb[0] = *(const f4v*)&W3[(long)(kn + ty) * 256 + j0 + tx * 4];
                pb[1] = *(const f4v*)&W3[(long)(kn + 16 + ty) * 256 + j0 + tx * 4];
            }
            #pragma unroll
            for (int k = 0; k < 32; ++k) {
                const float2 av2 = *(const float2*)&ldsA[k * 34 + ty * 2];
                const float4 bv4 = *(const float4*)&ldsB[k * 68 + tx * 4];
                const float wk = sw1[kk + k];
                dot[0] = fmaf(av2.x, wk, dot[0]);
                dot[1] = fmaf(av2.y, wk, dot[1]);
                acc[0][0] = fmaf(av2.x, bv4.x, acc[0][0]);
                acc[0][1] = fmaf(av2.x, bv4.y, acc[0][1]);
                acc[0][2] = fmaf(av2.x, bv4.z, acc[0][2]);
                acc[0][3] = fmaf(av2.x, bv4.w, acc[0][3]);
                acc[1][0] = fmaf(av2.y, bv4.x, acc[1][0]);
                acc[1][1] = fmaf(av2.y, bv4.y, acc[1][1]);
                acc[1][2] = fmaf(av2.y, bv4.z, acc[1][2]);
                acc[1][3] = fmaf(av2.y, bv4.w, acc[1][3]);
            }
            __syncthreads();
        }
        #pragma unroll
        for (int i = 0; i < 2; ++i) {
            const int r = r0 + ty * 2 + i;
            const float e1 = wvsx[b * 256 + r], e3 = bv[r];
            half4 hv, lv;
            #pragma unroll
            for (int j = 0; j < 4; ++j) {
                const int col = j0 + tx * 4 + j;
                const float val = acc[i][j] + e1 * u2[col] + e3 * v2[b * 256 + col];
                hv[j] = (_Float16)val;
                lv[j] = (_Float16)(val - (float)hv[j]);
            }
            const long o = (long)b * 65536 + (long)r * 256 + j0 + tx * 4;
            *(half4*)&Aph[o] = hv;
            *(half4*)&Apl[o] = lv;
            if (j0 == 0 && tx == 0)
                cvec[b * 256 + r] = dot[i] + e1 * s1[0] + e3 * s2[b];
        }
    }

    gbar(&bar[4], &bar[5], NBLK);

    // ================= STAGE 4: out = (Ap x + cvec 1^T) / S =================
    {
        _Float16* Ah = (_Float16*)smem;                 // 128*GP  halves = 10240 B
        _Float16* Al = (_Float16*)(smem + 10240);       // 10240 B
        _Float16* Bh = (_Float16*)(smem + 20480);       // 128*GPB halves = 9216 B
        _Float16* Bl = (_Float16*)(smem + 29696);       // 9216 B
        float*    xt = (float*)(smem + 38912);          // 32*132 floats = 16896 B

        const int n0 = (blk & 15) * 128;
        const int c0 = ((blk >> 4) & 1) * 128;
        const int b  = blk >> 5;
        const _Float16* Asrc_h = Aph + (long)b * 65536;
        const _Float16* Asrc_l = Apl + (long)b * 65536;
        const float* xb = x + (long)b * 524288;

        const int lane = t & 63, wave = t >> 6;
        const int wy = wave >> 1, wx = wave & 1;
        const int mIn = lane & 15, quad = lane >> 4;

        f4v acc[4][4] = {};
        const int aBase = (wy * 64 + mIn) * GP + quad * 8;
        const int bBase = (wx * 64 + mIn) * GPB + quad * 8;
        const int cn = t & 127;          // converter: n index
        const int ckh = (t >> 7) * 16;   // converter: k half-range

        int arow[2], ako[2], xk[4], xn[4];
        #pragma unroll
        for (int i = 0; i < 2; ++i) { const int idx = t + (i << 8); arow[i] = idx >> 2; ako[i] = (idx & 3) << 3; }
        #pragma unroll
        for (int p = 0; p < 4; ++p) { const int f = t + p * 256; xk[p] = f >> 5; xn[p] = f & 31; }

        uint4 pah[2], pal[2]; f4v px[4];
        #pragma unroll
        for (int i = 0; i < 2; ++i) {
            pah[i] = *(const uint4*)&Asrc_h[(long)(c0 + arow[i]) * 256 + ako[i]];
            pal[i] = *(const uint4*)&Asrc_l[(long)(c0 + arow[i]) * 256 + ako[i]];
        }
        #pragma unroll
        for (int p = 0; p < 4; ++p)
            px[p] = *(const f4v*)&xb[(long)xk[p] * 2048 + n0 + xn[p] * 4];

        for (int kk = 0; kk < 256; kk += 32) {
            #pragma unroll
            for (int i = 0; i < 2; ++i) {
                *(uint4*)&Ah[arow[i] * GP + ako[i]] = pah[i];
                *(uint4*)&Al[arow[i] * GP + ako[i]] = pal[i];
            }
            #pragma unroll
            for (int p = 0; p < 4; ++p)
                *(f4v*)&xt[xk[p] * 132 + xn[p] * 4] = px[p];
            __syncthreads();
            {
                _Float16 hs[16], ls[16];
                #pragma unroll
                for (int k = 0; k < 16; ++k) {
                    const float v = xt[(ckh + k) * 132 + cn];      // 2-way LDS read (free)
                    hs[k] = (_Float16)v;
                    ls[k] = (_Float16)(v - (float)hs[k]);
                }
                #pragma unroll
                for (int k2 = 0; k2 < 8; ++k2) {
                    half2v h2; h2[0] = hs[2 * k2]; h2[1] = hs[2 * k2 + 1];
                    half2v l2; l2[0] = ls[2 * k2]; l2[1] = ls[2 * k2 + 1];
                    *(half2v*)&Bh[cn * GPB + ckh + 2 * k2] = h2;   // 18-dword stride: 2-way (free)
                    *(half2v*)&Bl[cn * GPB + ckh + 2 * k2] = l2;
                }
            }
            __syncthreads();
            if (kk < 224) {
                const int kn = kk + 32;
                #pragma unroll
                for (int i = 0; i < 2; ++i) {
                    pah[i] = *(const uint4*)&Asrc_h[(long)(c0 + arow[i]) * 256 + kn + ako[i]];
                    pal[i] = *(const uint4*)&Asrc_l[(long)(c0 + arow[i]) * 256 + kn + ako[i]];
                }
                #pragma unroll
                for (int p = 0; p < 4; ++p)
                    px[p] = *(const f4v*)&xb[(long)(kn + xk[p]) * 2048 + n0 + xn[p] * 4];
            }
            #pragma unroll
            for (int ph = 0; ph < 3; ++ph) {
                const _Float16* As = (ph == 2) ? Al : Ah;
                const _Float16* Bs = (ph == 1) ? Bl : Bh;
                half8 af[4], bf[4];
                #pragma unroll
                for (int i = 0; i < 4; ++i) {
                    af[i] = *(const half8*)&As[aBase + i * 16 * GP];
                    const half4 b0 = *(const half4*)&Bs[bBase + i * 16 * GPB];
                    const half4 b1 = *(const half4*)&Bs[bBase + i * 16 * GPB + 4];
                    bf[i] = __builtin_shufflevector(b0, b1, 0, 1, 2, 3, 4, 5, 6, 7);
                }
                #pragma unroll
                for (int i = 0; i < 4; ++i)
                    #pragma unroll
                    for (int j = 0; j < 4; ++j)
                        acc[i][j] = __builtin_amdgcn_mfma_f32_16x16x32_f16(af[i], bf[j], acc[i][j], 0, 0, 0);
            }
            __syncthreads();
        }

        const float invS = 1.0f / S[0];
        float* ob = out + (long)b * 524288;
        const float* cv = cvec + b * 256;
        #pragma unroll
        for (int i = 0; i < 4; ++i)
            #pragma unroll
            for (int r = 0; r < 4; ++r) {
                const int row = c0 + wy * 64 + i * 16 + quad * 4 + r;
                const float c = cv[row];
                #pragma unroll
                for (int j = 0; j < 4; ++j) {
                    const int col = n0 + wx * 64 + j * 16 + mIn;
                    ob[(long)row * 2048 + col] = (acc[i][j][r] + c) * invS;
                }
            }
    }
}

extern "C" void kernel_launch(void* const* d_in, const int* in_sizes, int n_in,
                              void* d_out, int out_size, void* d_ws, size_t ws_size,
                              hipStream_t stream) {
    const float* x  = (const float*)d_in[0];
    const float* Wq = (const float*)d_in[1];
    const float* bq = (const float*)d_in[2];
    const float* Wk = (const float*)d_in[3];
    const float* bk = (const float*)d_in[4];
    const float* Wv = (const float*)d_in[5];
    const float* bv = (const float*)d_in[6];
    float* out = (float*)d_out;
    float* ws  = (float*)d_ws;

    float* T1     = ws;                  // 524288
    float* W3     = ws + 524288;         // 65536
    float* sxpart = ws + 589824;         // 8*2048
    float* wvsx   = ws + 606208;         // 2048
    float* v2     = ws + 608256;         // 2048
    float* cvec   = ws + 610304;         // 2048
    float* s2     = ws + 612352;         // 8
    float* u2     = ws + 612360;         // 256
    float* w1     = ws + 612616;         // 256
    float* s1     = ws + 612872;         // 1
    float* S      = ws + 612873;         // 1
    float* Gpart  = ws + 612880;         // 8*8*65536 = 4194304 (16 MB)
    _Float16* Aph = (_Float16*)(ws + 4807184);   // 524288 halves
    _Float16* Apl = Aph + 524288;                // +524288 halves -> ends at float ofs 5331472
    unsigned* bar = (unsigned*)(ws + 5331472);   // 6 u32 barrier slots

    // zero the grid-barrier slots (graph-capture-legal memset node)
    hipMemsetAsync(bar, 0, 64, stream);

    fused_kernel<<<dim3(256), dim3(256), 0, stream>>>(
        x, Wq, bq, Wk, bk, Wv, bv, out,
        T1, W3, sxpart, wvsx, v2, cvec, s2, u2, w1, s1, S, Gpart, Aph, Apl, bar);
}

// Round 3
// 144.907 us; speedup vs baseline: 1.4519x; 1.4519x over previous
//
#include <hip/hip_runtime.h>

// B=8, C=256, N=2048, fp32 in/out.
// attn_b = (Ap_b x_b + cvec_b 1^T) / S
//   Ap_b = T1_b W3 + wvsx_b (x) u2 + bv (x) v2_b      (f16 hi/lo split MFMA)
//   T1_b = Wv G_b,  W3 = Wq^T Wk,  G_b = x_b x_b^T (symmetric)
//   u2 = Wk^T bq, w1 = Wq^T bk, s1 = bq.bk, sx_b = rowsum(x_b)
//   v2_b = W3^T sx_b + N u2;  s2_b = sx.w1 + N s1;  S = sum_b [v2.sx + N s2]
//   cvec_b = T1.w1 + wvsx*s1 + bv*s2    (computed inside ap)
// 4 serial nodes. Round-2 fused experiment measured the stages at 1 block/CU:
// MfmaUtil 3%, VALU 7%, HBM 7% -> latency-bound at 1 wave/SIMD. THIS ROUND:
// 2 blocks/CU co-residency for the MFMA kernels via half-width tiles:
//   k1 gemmG: 128x64 tiles, 6 sub-tiles x 64 (b,ks) = 384 blocks (LDS 30KB)
//   k4 gemmF: n-tile 64, grid (32,2,8) = 512 blocks (LDS 38KB)
// Per-element accumulation order unchanged -> identical absmax. W3/misc and
// k2 small jobs moved to low block indices (dispatch wave 1).

typedef _Float16 half8 __attribute__((ext_vector_type(8)));
typedef _Float16 half4 __attribute__((ext_vector_type(4)));
typedef _Float16 half2v __attribute__((ext_vector_type(2)));
typedef float f4v __attribute__((ext_vector_type(4)));

#define GP  40   // LDS pitch (halves), A panels / gemmG (16B-aligned rows)
#define GPB 36   // gemmF B panel pitch: 18-dword row stride -> 2-way (free) banking

// ---------------- K1: W3 (0..15) | u2/w1/s1 (16) | gemmG 128x64 (17..400) ----------------
__launch_bounds__(256)
__global__ void k1_kernel(const float* __restrict__ x, const float* __restrict__ Wq,
                          const float* __restrict__ Wk, const float* __restrict__ bq,
                          const float* __restrict__ bk, float* __restrict__ sxpart,
                          float* __restrict__ W3, float* __restrict__ u2,
                          float* __restrict__ w1, float* __restrict__ s1,
                          float* __restrict__ S, float* __restrict__ Gpart) {
    __shared__ __align__(16) char smem[30720];
    const int blk = blockIdx.x, t = threadIdx.x;
    if (blk >= 17) {
        // gemmG: G_b = x_b x_b^T, splitK=8, 128x64 output tiles.
        // sub 0..5 = (tileId 0..2) x (colHalf 0..1); the 6 sub-tiles of one
        // (b,ks) are 64 apart -> same blk%8 -> same XCD -> x k-slice L2 reuse.
        _Float16* Ah = (_Float16*)smem;        // 128*GP halves
        _Float16* Al = Ah + 128 * GP;
        _Float16* Bh = Al + 128 * GP;          // 64*GP halves (off-diag only)
        _Float16* Bl = Bh + 64 * GP;
        const int gb = blk - 17;
        const int sub = gb >> 6;               // 0..5
        const int y = gb & 63;                 // 0..63
        const int b = y >> 3, ks = y & 7;
        const int tileId = sub >> 1, ch = sub & 1;
        const int r0 = (tileId == 2) ? 128 : 0;
        const int c0 = ((tileId == 0) ? 0 : 128) + ch * 64;
        const bool diag = (tileId != 1);
        const bool doRS = diag && (ch == 0);
        const float* xb = x + (long)b * 524288;

        const int lane = t & 63, wave = t >> 6;
        const int wy = wave >> 1, wx = wave & 1;
        const int mIn = lane & 15, quad = lane >> 4;

        f4v acc[4][2] = {};
        const int aBase = (wy * 64 + mIn) * GP + quad * 8;
        const int bBase = diag ? ((ch * 64 + wx * 32 + mIn) * GP + quad * 8)   // read from A panel
                               : ((wx * 32 + mIn) * GP + quad * 8);            // read from B panel
        const int srow = t >> 3;               // 0..31
        const int skq  = (t & 7) * 4;          // 0..28
        float rs[4] = {};                      // rowsum partials (doRS only)

        float4 pa[4], pb[2];
        int kk = ks * 256;
        #pragma unroll
        for (int i = 0; i < 4; ++i)
            pa[i] = *(const float4*)&xb[(long)(r0 + srow + i * 32) * 2048 + kk + skq];
        if (!diag) {
            #pragma unroll
            for (int i = 0; i < 2; ++i)
                pb[i] = *(const float4*)&xb[(long)(c0 + srow + i * 32) * 2048 + kk + skq];
        }

        for (int kb = 0; kb < 8; ++kb) {
            if (kb) __syncthreads();
            #pragma unroll
            for (int i = 0; i < 4; ++i) {
                const int row = srow + i * 32;
                half4 hv, lv;
                hv[0] = (_Float16)pa[i].x; lv[0] = (_Float16)(pa[i].x - (float)hv[0]);
                hv[1] = (_Float16)pa[i].y; lv[1] = (_Float16)(pa[i].y - (float)hv[1]);
                hv[2] = (_Float16)pa[i].z; lv[2] = (_Float16)(pa[i].z - (float)hv[2]);
                hv[3] = (_Float16)pa[i].w; lv[3] = (_Float16)(pa[i].w - (float)hv[3]);
                *(half4*)&Ah[row * GP + skq] = hv;
                *(half4*)&Al[row * GP + skq] = lv;
                if (doRS) rs[i] += pa[i].x + pa[i].y + pa[i].z + pa[i].w;
            }
            if (!diag) {
                #pragma unroll
                for (int i = 0; i < 2; ++i) {
                    const int row = srow + i * 32;
                    half4 hb, lb;
                    hb[0] = (_Float16)pb[i].x; lb[0] = (_Float16)(pb[i].x - (float)hb[0]);
                    hb[1] = (_Float16)pb[i].y; lb[1] = (_Float16)(pb[i].y - (float)hb[1]);
                    hb[2] = (_Float16)pb[i].z; lb[2] = (_Float16)(pb[i].z - (float)hb[2]);
                    hb[3] = (_Float16)pb[i].w; lb[3] = (_Float16)(pb[i].w - (float)hb[3]);
                    *(half4*)&Bh[row * GP + skq] = hb;
                    *(half4*)&Bl[row * GP + skq] = lb;
                }
            }
            __syncthreads();
            kk += 32;
            if (kb < 7) {
                #pragma unroll
                for (int i = 0; i < 4; ++i)
                    pa[i] = *(const float4*)&xb[(long)(r0 + srow + i * 32) * 2048 + kk + skq];
                if (!diag) {
                    #pragma unroll
                    for (int i = 0; i < 2; ++i)
                        pb[i] = *(const float4*)&xb[(long)(c0 + srow + i * 32) * 2048 + kk + skq];
                }
            }
            const _Float16* BhP = diag ? Ah : Bh;
            const _Float16* BlP = diag ? Al : Bl;
            #pragma unroll
            for (int ph = 0; ph < 3; ++ph) {
                const _Float16* As = (ph == 2) ? Al : Ah;
                const _Float16* Bs = (ph == 1) ? BlP : BhP;
                half8 af[4], bf[2];
                #pragma unroll
                for (int i = 0; i < 4; ++i)
                    af[i] = *(const half8*)&As[aBase + i * 16 * GP];
                #pragma unroll
                for (int j = 0; j < 2; ++j)
                    bf[j] = *(const half8*)&Bs[bBase + j * 16 * GP];
                #pragma unroll
                for (int i = 0; i < 4; ++i)
                    #pragma unroll
                    for (int j = 0; j < 2; ++j)
                        acc[i][j] = __builtin_amdgcn_mfma_f32_16x16x32_f16(af[i], bf[j], acc[i][j], 0, 0, 0);
            }
        }

        if (doRS) {
            #pragma unroll
            for (int i = 0; i < 4; ++i) {
                rs[i] += __shfl_xor(rs[i], 1);
                rs[i] += __shfl_xor(rs[i], 2);
                rs[i] += __shfl_xor(rs[i], 4);
            }
            if ((t & 7) == 0) {
                #pragma unroll
                for (int i = 0; i < 4; ++i)
                    sxpart[ks * 2048 + b * 256 + r0 + srow + i * 32] = rs[i];
            }
        }

        float* D = Gpart + ((long)(ks * 8 + b) << 16);
        #pragma unroll
        for (int i = 0; i < 4; ++i)
            #pragma unroll
            for (int j = 0; j < 2; ++j) {
                const int row = r0 + wy * 64 + i * 16 + quad * 4;
                const int col = c0 + wx * 32 + j * 16 + mIn;
                #pragma unroll
                for (int r = 0; r < 4; ++r)
                    D[(row + r) * 256 + col] = acc[i][j][r];
                if (tileId == 1)
                    *(float4*)&D[(long)col * 256 + row] =
                        make_float4(acc[i][j][0], acc[i][j][1], acc[i][j][2], acc[i][j][3]);
            }
    } else if (blk < 16) {
        float* ldsA = (float*)smem;
        float* ldsB = ldsA + 16 * 68;
        const int tile = blk;
        const int r0 = (tile >> 2) * 64, j0 = (tile & 3) * 64;
        const int tx = t & 15, ty = t >> 4;
        float acc[4][4] = {};
        for (int kk = 0; kk < 256; kk += 16) {
            *(float4*)&ldsA[ty * 68 + tx * 4] = *(const float4*)&Wq[(long)(kk + ty) * 256 + r0 + tx * 4];
            *(float4*)&ldsB[ty * 68 + tx * 4] = *(const float4*)&Wk[(long)(kk + ty) * 256 + j0 + tx * 4];
            __syncthreads();
            #pragma unroll
            for (int k = 0; k < 16; ++k) {
                const float4 av4 = *(const float4*)&ldsA[k * 68 + ty * 4];
                const float4 bv4 = *(const float4*)&ldsB[k * 68 + tx * 4];
                const float ar[4] = {av4.x, av4.y, av4.z, av4.w};
                const float br[4] = {bv4.x, bv4.y, bv4.z, bv4.w};
                #pragma unroll
                for (int i = 0; i < 4; ++i)
                    #pragma unroll
                    for (int j = 0; j < 4; ++j)
                        acc[i][j] = fmaf(ar[i], br[j], acc[i][j]);
            }
            __syncthreads();
        }
        #pragma unroll
        for (int i = 0; i < 4; ++i)
            *(float4*)&W3[(long)(r0 + ty * 4 + i) * 256 + j0 + tx * 4] =
                make_float4(acc[i][0], acc[i][1], acc[i][2], acc[i][3]);
    } else {                                   // blk == 16
        float* sbq = (float*)smem;
        float* sbk = sbq + 256;
        float* red = sbk + 256;
        if (t == 0) S[0] = 0.0f;
        sbq[t] = bq[t]; sbk[t] = bk[t];
        __syncthreads();
        float u = 0.0f, w = 0.0f;
        #pragma unroll 8
        for (int c = 0; c < 256; ++c) {
            u = fmaf(Wk[(long)c * 256 + t], sbq[c], u);   // coalesced columns
            w = fmaf(Wq[(long)c * 256 + t], sbk[c], w);
        }
        u2[t] = u; w1[t] = w;
        red[t] = sbq[t] * sbk[t]; __syncthreads();
        for (int h = 128; h > 0; h >>= 1) { if (t < h) red[t] += red[t + h]; __syncthreads(); }
        if (t == 0) s1[0] = red[0];
    }
}

// ---------------- K2: prep2 (0..7) | wvsx (8..15) | t1 32x64 (16..271) ----------------
__launch_bounds__(256)
__global__ void k2_kernel(const float* __restrict__ Wv, const float* __restrict__ Gpart,
                          const float* __restrict__ W3, const float* __restrict__ u2,
                          const float* __restrict__ w1, const float* __restrict__ s1p,
                          const float* __restrict__ sxpart, float* __restrict__ T1,
                          float* __restrict__ v2, float* __restrict__ s2,
                          float* __restrict__ wvsx, float* __restrict__ S) {
    __shared__ __align__(16) char smem[40960];
    const int blk = blockIdx.x, t = threadIdx.x;
    if (blk >= 16) {
        // T1_b = Wv * G_b, 32x64 tiles -> 256 blocks. The 8 r0-blocks sharing
        // one (b,j0) Gpart panel are 32 apart -> same blk%8 -> same XCD.
        float* ldsA = (float*)smem;            // [32 k][34] transposed Wv panel
        float* ldsB = ldsA + 32 * 34;          // [32 k][68] reduced G panel
        const int gb = blk - 16;
        const int r0 = (gb >> 5) * 32;         // 0..224
        const int g  = gb & 31;
        const int b  = g >> 2;
        const int j0 = (g & 3) * 64;
        const int tx = t & 15, ty = t >> 4;
        const int ar = t >> 3, ak4 = (t & 7) * 4;
        const float* Gb = Gpart + (long)b * 65536 + j0;
        float acc[2][4] = {};

        f4v pa, pg[2][8];
        pa = *(const f4v*)&Wv[(long)(r0 + ar) * 256 + ak4];
        #pragma unroll
        for (int s = 0; s < 2; ++s)
            #pragma unroll
            for (int ksl = 0; ksl < 8; ++ksl)
                pg[s][ksl] = *(const f4v*)&Gb[(long)ksl * 524288 + (long)(s * 16 + ty) * 256 + tx * 4];

        for (int c = 0; c < 8; ++c) {
            const int kk = c * 32;
            ldsA[(ak4 + 0) * 34 + ar] = pa[0];
            ldsA[(ak4 + 1) * 34 + ar] = pa[1];
            ldsA[(ak4 + 2) * 34 + ar] = pa[2];
            ldsA[(ak4 + 3) * 34 + ar] = pa[3];
            #pragma unroll
            for (int s = 0; s < 2; ++s) {
                f4v bs = pg[s][0];
                #pragma unroll
                for (int ksl = 1; ksl < 8; ++ksl) bs += pg[s][ksl];
                *(f4v*)&ldsB[(s * 16 + ty) * 68 + tx * 4] = bs;
            }
            __syncthreads();
            if (c < 7) {                       // issue next chunk's loads; FMA hides latency
                const int kn = kk + 32;
                pa = *(const f4v*)&Wv[(long)(r0 + ar) * 256 + kn + ak4];
                #pragma unroll
                for (int s = 0; s < 2; ++s)
                    #pragma unroll
                    for (int ksl = 0; ksl < 8; ++ksl)
                        pg[s][ksl] = *(const f4v*)&Gb[(long)ksl * 524288 + (long)(kn + s * 16 + ty) * 256 + tx * 4];
            }
            #pragma unroll
            for (int k = 0; k < 32; ++k) {
                const float2 av2 = *(const float2*)&ldsA[k * 34 + ty * 2];
                const float4 bv4 = *(const float4*)&ldsB[k * 68 + tx * 4];
                acc[0][0] = fmaf(av2.x, bv4.x, acc[0][0]);
                acc[0][1] = fmaf(av2.x, bv4.y, acc[0][1]);
                acc[0][2] = fmaf(av2.x, bv4.z, acc[0][2]);
                acc[0][3] = fmaf(av2.x, bv4.w, acc[0][3]);
                acc[1][0] = fmaf(av2.y, bv4.x, acc[1][0]);
                acc[1][1] = fmaf(av2.y, bv4.y, acc[1][1]);
                acc[1][2] = fmaf(av2.y, bv4.z, acc[1][2]);
                acc[1][3] = fmaf(av2.y, bv4.w, acc[1][3]);
            }
            __syncthreads();
        }
        float* D = T1 + (long)b * 65536;
        #pragma unroll
        for (int i = 0; i < 2; ++i)
            *(float4*)&D[(long)(r0 + ty * 2 + i) * 256 + j0 + tx * 4] =
                make_float4(acc[i][0], acc[i][1], acc[i][2], acc[i][3]);
    } else if (blk < 8) {
        float* ssx = (float*)smem;
        float* red = ssx + 256;
        const int b = blk, j = t;
        float sxv = 0.0f;
        #pragma unroll
        for (int ks = 0; ks < 8; ++ks) sxv += sxpart[ks * 2048 + b * 256 + j];
        ssx[j] = sxv;
        __syncthreads();
        float vr = 0.0f;
        #pragma unroll 8
        for (int c = 0; c < 256; ++c) vr = fmaf(W3[(long)c * 256 + j], ssx[c], vr); // coalesced
        const float v2j = vr + 2048.0f * u2[j];
        v2[b * 256 + j] = v2j;
        red[j] = v2j * sxv; __syncthreads();
        for (int h = 128; h > 0; h >>= 1) { if (j < h) red[j] += red[j + h]; __syncthreads(); }
        const float sd1 = red[0];
        __syncthreads();
        red[j] = sxv * w1[j]; __syncthreads();
        for (int h = 128; h > 0; h >>= 1) { if (j < h) red[j] += red[j + h]; __syncthreads(); }
        if (j == 0) {
            const float s2v = red[0] + 2048.0f * s1p[0];
            s2[b] = s2v;
            atomicAdd(S, sd1 + 2048.0f * s2v);
        }
    } else {                                   // blk 8..15: wvsx
        float* wtile = (float*)smem;           // 32 x 256
        float* sxs = wtile + 8192;             // 2048
        const int r0w = (blk - 8) * 32;
        #pragma unroll
        for (int p = 0; p < 8; ++p) {
            const int f = t + p * 256;
            const int row = f >> 6, c4 = f & 63;
            *(float4*)&wtile[row * 256 + c4 * 4] = *(const float4*)&Wv[(long)(r0w + row) * 256 + c4 * 4];
        }
        #pragma unroll
        for (int p = 0; p < 8; ++p) {
            const int f = t + p * 256;
            float s = 0.0f;
            #pragma unroll
            for (int ks = 0; ks < 8; ++ks) s += sxpart[ks * 2048 + f];
            sxs[f] = s;
        }
        __syncthreads();
        const int r = t >> 3, q = t & 7;       // 32 rows x 8 k-groups
        float acc[8] = {};
        for (int ci = 0; ci < 32; ++ci) {
            const float wv = wtile[r * 256 + q * 32 + ci];
            #pragma unroll
            for (int b = 0; b < 8; ++b) acc[b] = fmaf(wv, sxs[b * 256 + q * 32 + ci], acc[b]);
        }
        #pragma unroll
        for (int b = 0; b < 8; ++b) {
            acc[b] += __shfl_xor(acc[b], 1);
            acc[b] += __shfl_xor(acc[b], 2);
            acc[b] += __shfl_xor(acc[b], 4);
        }
        if (q == 0) {
            #pragma unroll
            for (int b = 0; b < 8; ++b) wvsx[b * 256 + r0w + r] = acc[b];
        }
    }
}

// ---------------- K3: Ap = T1 W3 + wvsx(x)u2 + bv(x)v2 -> f16 hi/lo; cvec fold ----------------
// 32x64 tiles, grid (4,8,8) = 256 blocks + reg prefetch.
__launch_bounds__(256)
__global__ void ap_kernel(const float* __restrict__ T1, const float* __restrict__ W3,
                          const float* __restrict__ wvsx, const float* __restrict__ u2,
                          const float* __restrict__ bv, const float* __restrict__ v2,
                          const float* __restrict__ w1, const float* __restrict__ s1p,
                          const float* __restrict__ s2, _Float16* __restrict__ Aph,
                          _Float16* __restrict__ Apl, float* __restrict__ cvec) {
    __shared__ __align__(16) float ldsA[32 * 34];   // [32 k][34] transposed T1 panel
    __shared__ __align__(16) float ldsB[32 * 68];   // [32 k][68] W3 panel
    __shared__ float sw1[256];
    const int b = blockIdx.z;
    const int r0 = blockIdx.y * 32, j0 = blockIdx.x * 64;
    const float* A = T1 + (long)b * 65536;
    const int t = threadIdx.x, tx = t & 15, ty = t >> 4;
    const int ar = t >> 3, ak4 = (t & 7) * 4;
    sw1[t] = w1[t];
    float acc[2][4] = {};
    float dot[2] = {};

    f4v pa, pb[2];
    pa = *(const f4v*)&A[(long)(r0 + ar) * 256 + ak4];
    pb[0] = *(const f4v*)&W3[(long)(ty) * 256 + j0 + tx * 4];
    pb[1] = *(const f4v*)&W3[(long)(16 + ty) * 256 + j0 + tx * 4];

    for (int c = 0; c < 8; ++c) {
        const int kk = c * 32;
        ldsA[(ak4 + 0) * 34 + ar] = pa[0];
        ldsA[(ak4 + 1) * 34 + ar] = pa[1];
        ldsA[(ak4 + 2) * 34 + ar] = pa[2];
        ldsA[(ak4 + 3) * 34 + ar] = pa[3];
        *(f4v*)&ldsB[ty * 68 + tx * 4] = pb[0];
        *(f4v*)&ldsB[(16 + ty) * 68 + tx * 4] = pb[1];
        __syncthreads();
        if (c < 7) {                            // prefetch next chunk under FMA
            const int kn = kk + 32;
            pa = *(const f4v*)&A[(long)(r0 + ar) * 256 + kn + ak4];
            pb[0] = *(const f4v*)&W3[(long)(kn + ty) * 256 + j0 + tx * 4];
            pb[1] = *(const f4v*)&W3[(long)(kn + 16 + ty) * 256 + j0 + tx * 4];
        }
        #pragma unroll
        for (int k = 0; k < 32; ++k) {
            const float2 av2 = *(const float2*)&ldsA[k * 34 + ty * 2];
            const float4 bv4 = *(const float4*)&ldsB[k * 68 + tx * 4];
            const float wk = sw1[kk + k];
            dot[0] = fmaf(av2.x, wk, dot[0]);
            dot[1] = fmaf(av2.y, wk, dot[1]);
            acc[0][0] = fmaf(av2.x, bv4.x, acc[0][0]);
            acc[0][1] = fmaf(av2.x, bv4.y, acc[0][1]);
            acc[0][2] = fmaf(av2.x, bv4.z, acc[0][2]);
            acc[0][3] = fmaf(av2.x, bv4.w, acc[0][3]);
            acc[1][0] = fmaf(av2.y, bv4.x, acc[1][0]);
            acc[1][1] = fmaf(av2.y, bv4.y, acc[1][1]);
            acc[1][2] = fmaf(av2.y, bv4.z, acc[1][2]);
            acc[1][3] = fmaf(av2.y, bv4.w, acc[1][3]);
        }
        __syncthreads();
    }
    #pragma unroll
    for (int i = 0; i < 2; ++i) {
        const int r = r0 + ty * 2 + i;
        const float e1 = wvsx[b * 256 + r], e3 = bv[r];
        half4 hv, lv;
        #pragma unroll
        for (int j = 0; j < 4; ++j) {
            const int col = j0 + tx * 4 + j;
            const float val = acc[i][j] + e1 * u2[col] + e3 * v2[b * 256 + col];
            hv[j] = (_Float16)val;
            lv[j] = (_Float16)(val - (float)hv[j]);
        }
        const long o = (long)b * 65536 + (long)r * 256 + j0 + tx * 4;
        *(half4*)&Aph[o] = hv;
        *(half4*)&Apl[o] = lv;
        if (j0 == 0 && tx == 0)
            cvec[b * 256 + r] = dot[i] + e1 * s1p[0] + e3 * s2[b];
    }
}

// ---------------- K4: out = (Ap x + cvec 1^T) / S ; 128x64 tiles, grid (32,2,8) ----------------
__launch_bounds__(256)
__global__ void gemmF_mfma(const _Float16* __restrict__ Aph, const _Float16* __restrict__ Apl,
                           const float* __restrict__ x, const float* __restrict__ Sptr,
                           const float* __restrict__ cvec, float* __restrict__ out) {
    __shared__ __align__(16) _Float16 Ah[128 * GP];
    __shared__ __align__(16) _Float16 Al[128 * GP];
    __shared__ __align__(16) _Float16 Bh[64 * GPB];
    __shared__ __align__(16) _Float16 Bl[64 * GPB];
    __shared__ __align__(16) float xt[32 * 68];

    const int n0 = blockIdx.x * 64;
    const int c0 = blockIdx.y * 128;
    const int b = blockIdx.z;
    const _Float16* Asrc_h = Aph + (long)b * 65536;
    const _Float16* Asrc_l = Apl + (long)b * 65536;
    const float* xb = x + (long)b * 524288;

    const int t = threadIdx.x;
    const int lane = t & 63, wave = t >> 6;
    const int wy = wave >> 1, wx = wave & 1;
    const int mIn = lane & 15, quad = lane >> 4;

    f4v acc[4][2] = {};
    const int aBase = (wy * 64 + mIn) * GP + quad * 8;
    const int bBase = (wx * 32 + mIn) * GPB + quad * 8;
    const int cn = t & 63;           // converter: n index (0..63)
    const int ck = (t >> 6) * 8;     // converter: k group base (0,8,16,24)

    int arow[2], ako[2], xk[2], xn[2];
    #pragma unroll
    for (int i = 0; i < 2; ++i) { const int idx = t + (i << 8); arow[i] = idx >> 2; ako[i] = (idx & 3) << 3; }
    #pragma unroll
    for (int p = 0; p < 2; ++p) { const int f = t + p * 256; xk[p] = f >> 4; xn[p] = f & 15; }

    uint4 pah[2], pal[2]; f4v px[2];
    #pragma unroll
    for (int i = 0; i < 2; ++i) {
        pah[i] = *(const uint4*)&Asrc_h[(long)(c0 + arow[i]) * 256 + ako[i]];
        pal[i] = *(const uint4*)&Asrc_l[(long)(c0 + arow[i]) * 256 + ako[i]];
    }
    #pragma unroll
    for (int p = 0; p < 2; ++p)
        px[p] = *(const f4v*)&xb[(long)xk[p] * 2048 + n0 + xn[p] * 4];

    for (int kk = 0; kk < 256; kk += 32) {
        #pragma unroll
        for (int i = 0; i < 2; ++i) {
            *(uint4*)&Ah[arow[i] * GP + ako[i]] = pah[i];
            *(uint4*)&Al[arow[i] * GP + ako[i]] = pal[i];
        }
        #pragma unroll
        for (int p = 0; p < 2; ++p)
            *(f4v*)&xt[xk[p] * 68 + xn[p] * 4] = px[p];
        __syncthreads();
        {
            _Float16 hs[8], ls[8];
            #pragma unroll
            for (int k = 0; k < 8; ++k) {
                const float v = xt[(ck + k) * 68 + cn];        // stride-1 lanes: 2-way (free)
                hs[k] = (_Float16)v;
                ls[k] = (_Float16)(v - (float)hs[k]);
            }
            #pragma unroll
            for (int k2 = 0; k2 < 4; ++k2) {
                half2v h2; h2[0] = hs[2 * k2]; h2[1] = hs[2 * k2 + 1];
                half2v l2; l2[0] = ls[2 * k2]; l2[1] = ls[2 * k2 + 1];
                *(half2v*)&Bh[cn * GPB + ck + 2 * k2] = h2;    // 18-dword stride: 2-way (free)
                *(half2v*)&Bl[cn * GPB + ck + 2 * k2] = l2;
            }
        }
        __syncthreads();
        if (kk < 224) {                         // prefetch next tile under MFMA phases
            const int kn = kk + 32;
            #pragma unroll
            for (int i = 0; i < 2; ++i) {
                pah[i] = *(const uint4*)&Asrc_h[(long)(c0 + arow[i]) * 256 + kn + ako[i]];
                pal[i] = *(const uint4*)&Asrc_l[(long)(c0 + arow[i]) * 256 + kn + ako[i]];
            }
            #pragma unroll
            for (int p = 0; p < 2; ++p)
                px[p] = *(const f4v*)&xb[(long)(kn + xk[p]) * 2048 + n0 + xn[p] * 4];
        }
        #pragma unroll
        for (int ph = 0; ph < 3; ++ph) {
            const _Float16* As = (ph == 2) ? Al : Ah;
            const _Float16* Bs = (ph == 1) ? Bl : Bh;
            half8 af[4], bf[2];
            #pragma unroll
            for (int i = 0; i < 4; ++i)
                af[i] = *(const half8*)&As[aBase + i * 16 * GP];
            #pragma unroll
            for (int j = 0; j < 2; ++j) {
                const half4 b0 = *(const half4*)&Bs[bBase + j * 16 * GPB];
                const half4 b1 = *(const half4*)&Bs[bBase + j * 16 * GPB + 4];
                bf[j] = __builtin_shufflevector(b0, b1, 0, 1, 2, 3, 4, 5, 6, 7);
            }
            #pragma unroll
            for (int i = 0; i < 4; ++i)
                #pragma unroll
                for (int j = 0; j < 2; ++j)
                    acc[i][j] = __builtin_amdgcn_mfma_f32_16x16x32_f16(af[i], bf[j], acc[i][j], 0, 0, 0);
        }
        __syncthreads();
    }

    const float invS = 1.0f / Sptr[0];
    float* ob = out + (long)b * 524288;
    const float* cv = cvec + b * 256;
    #pragma unroll
    for (int i = 0; i < 4; ++i)
        #pragma unroll
        for (int r = 0; r < 4; ++r) {
            const int row = c0 + wy * 64 + i * 16 + quad * 4 + r;
            const float c = cv[row];
            #pragma unroll
            for (int j = 0; j < 2; ++j) {
                const int col = n0 + wx * 32 + j * 16 + mIn;
                ob[(long)row * 2048 + col] = (acc[i][j][r] + c) * invS;
            }
        }
}

extern "C" void kernel_launch(void* const* d_in, const int* in_sizes, int n_in,
                              void* d_out, int out_size, void* d_ws, size_t ws_size,
                              hipStream_t stream) {
    const float* x  = (const float*)d_in[0];
    const float* Wq = (const float*)d_in[1];
    const float* bq = (const float*)d_in[2];
    const float* Wk = (const float*)d_in[3];
    const float* bk = (const float*)d_in[4];
    const float* Wv = (const float*)d_in[5];
    const float* bv = (const float*)d_in[6];
    float* out = (float*)d_out;
    float* ws  = (float*)d_ws;

    float* T1     = ws;                  // 524288
    float* W3     = ws + 524288;         // 65536
    float* sxpart = ws + 589824;         // 8*2048
    float* wvsx   = ws + 606208;         // 2048
    float* v2     = ws + 608256;         // 2048
    float* cvec   = ws + 610304;         // 2048
    float* s2     = ws + 612352;         // 8
    float* u2     = ws + 612360;         // 256
    float* w1     = ws + 612616;         // 256
    float* s1     = ws + 612872;         // 1
    float* S      = ws + 612873;         // 1
    float* Gpart  = ws + 612880;         // 8*8*65536 = 4194304 (16 MB)
    _Float16* Aph = (_Float16*)(ws + 4807184);   // 524288 halves
    _Float16* Apl = Aph + 524288;                // total ws ~21 MB

    k1_kernel<<<dim3(401), 256, 0, stream>>>(x, Wq, Wk, bq, bk, sxpart, W3, u2, w1, s1, S, Gpart);
    k2_kernel<<<dim3(272), 256, 0, stream>>>(Wv, Gpart, W3, u2, w1, s1, sxpart, T1, v2, s2, wvsx, S);
    ap_kernel<<<dim3(4, 8, 8), 256, 0, stream>>>(T1, W3, wvsx, u2, bv, v2, w1, s1, s2, Aph, Apl, cvec);
    gemmF_mfma<<<dim3(32, 2, 8), 256, 0, stream>>>(Aph, Apl, x, S, cvec, out);
}

// Round 5
// 136.473 us; speedup vs baseline: 1.5416x; 1.0618x over previous
//
#include <hip/hip_runtime.h>

// B=8, C=256, N=2048, fp32 in/out.
// attn_b = (Ap_b x_b + cvec_b 1^T) / S
//   Ap_b = T1_b W3 + wvsx_b (x) u2 + bv (x) v2_b      (f16 hi/lo split MFMA)
//   T1_b = Wv G_b,  W3 = Wq^T Wk,  G_b = x_b x_b^T (symmetric)
//   u2 = Wk^T bq, w1 = Wq^T bk, s1 = bq.bk, sx_b = rowsum(x_b)
//   v2_b = W3^T sx_b + N u2;  s2_b = sx.w1 + N s1;  S = sum_b [v2.sx + N s2]
//   cvec_b = T1.w1 + wvsx*s1 + bv*s2    (computed inside ap)
// 4 serial nodes. Rounds 2-3 established the regime: latency-bound at low
// waves/SIMD (fused probe: MfmaUtil 3%, VALU 7%, HBM 7%); round-3's 2-blk/CU
// push on k1/k4 gave -9.4us. THIS ROUND (resubmit of round-4; bench infra
// failed, kernel audited clean): uniform occupancy push on ALL kernels:
//   k1 gemmG: 64x64 upper-triangle tiles (10/(b,ks), transpose-write off-diag)
//             -> 640 blocks (2.5/CU), LDS 20KB, acc 16 VGPR
//   k2 t1:    32x32 tiles -> 512 blocks (2/CU)
//   ap:       32x32 tiles, grid (8,8,8) = 512 blocks (2/CU)
//   k4 gemmF: 64x64 tiles, grid (32,4,8) = 1024 blocks (4/CU), LDS 28KB
// Per-element K/phase accumulation order preserved everywhere.

typedef _Float16 half8 __attribute__((ext_vector_type(8)));
typedef _Float16 half4 __attribute__((ext_vector_type(4)));
typedef _Float16 half2v __attribute__((ext_vector_type(2)));
typedef float f4v __attribute__((ext_vector_type(4)));

#define GP  40   // LDS pitch (halves), A panels / gemmG (16B-aligned rows)
#define GPB 36   // gemmF B panel pitch: 18-dword row stride -> 2-way (free) banking

// ---------------- K1: W3 (0..15) | u2/w1/s1 (16) | gemmG 64x64 triangle (17..656) ----------------
__launch_bounds__(256)
__global__ void k1_kernel(const float* __restrict__ x, const float* __restrict__ Wq,
                          const float* __restrict__ Wk, const float* __restrict__ bq,
                          const float* __restrict__ bk, float* __restrict__ sxpart,
                          float* __restrict__ W3, float* __restrict__ u2,
                          float* __restrict__ w1, float* __restrict__ s1,
                          float* __restrict__ S, float* __restrict__ Gpart) {
    __shared__ __align__(16) char smem[20480];
    const int blk = blockIdx.x, t = threadIdx.x;
    if (blk >= 17) {
        // gemmG: G_b = x_b x_b^T, splitK=8, 64x64 upper-triangle tiles.
        // The 10 sub-tiles of one (b,ks) are 64 apart -> same blk%8 -> same XCD
        // -> shared x k-slice rows hit that XCD's L2.
        _Float16* Ah = (_Float16*)smem;        // 64*GP halves
        _Float16* Al = Ah + 64 * GP;
        _Float16* Bh = Al + 64 * GP;           // off-diag only
        _Float16* Bl = Bh + 64 * GP;
        const int gb = blk - 17;
        const int sub = gb >> 6;               // 0..9
        const int y = gb & 63;                 // 0..63
        const int b = y >> 3, ks = y & 7;
        const int ti = (sub < 4) ? 0 : (sub < 7) ? 1 : (sub < 9) ? 2 : 3;
        const int tj = (sub < 4) ? sub : (sub < 7) ? sub - 3 : (sub < 9) ? sub - 5 : 3;
        const int r0 = ti * 64, c0 = tj * 64;
        const bool diag = (ti == tj);
        const float* xb = x + (long)b * 524288;

        const int lane = t & 63, wave = t >> 6;
        const int wy = wave >> 1, wx = wave & 1;
        const int mIn = lane & 15, quad = lane >> 4;

        f4v acc[2][2] = {};
        const int aBase = (wy * 32 + mIn) * GP + quad * 8;
        const int bBase = (wx * 32 + mIn) * GP + quad * 8;
        const int srow = t >> 3;               // 0..31
        const int skq  = (t & 7) * 4;          // 0..28
        float rs[2] = {};                      // rowsum partials (diag only)

        float4 pa[2], pb[2];
        int kk = ks * 256;
        #pragma unroll
        for (int i = 0; i < 2; ++i)
            pa[i] = *(const float4*)&xb[(long)(r0 + srow + i * 32) * 2048 + kk + skq];
        if (!diag) {
            #pragma unroll
            for (int i = 0; i < 2; ++i)
                pb[i] = *(const float4*)&xb[(long)(c0 + srow + i * 32) * 2048 + kk + skq];
        }

        for (int kb = 0; kb < 8; ++kb) {
            if (kb) __syncthreads();
            #pragma unroll
            for (int i = 0; i < 2; ++i) {
                const int row = srow + i * 32;
                half4 hv, lv;
                hv[0] = (_Float16)pa[i].x; lv[0] = (_Float16)(pa[i].x - (float)hv[0]);
                hv[1] = (_Float16)pa[i].y; lv[1] = (_Float16)(pa[i].y - (float)hv[1]);
                hv[2] = (_Float16)pa[i].z; lv[2] = (_Float16)(pa[i].z - (float)hv[2]);
                hv[3] = (_Float16)pa[i].w; lv[3] = (_Float16)(pa[i].w - (float)hv[3]);
                *(half4*)&Ah[row * GP + skq] = hv;
                *(half4*)&Al[row * GP + skq] = lv;
                if (diag) rs[i] += pa[i].x + pa[i].y + pa[i].z + pa[i].w;
            }
            if (!diag) {
                #pragma unroll
                for (int i = 0; i < 2; ++i) {
                    const int row = srow + i * 32;
                    half4 hb, lb;
                    hb[0] = (_Float16)pb[i].x; lb[0] = (_Float16)(pb[i].x - (float)hb[0]);
                    hb[1] = (_Float16)pb[i].y; lb[1] = (_Float16)(pb[i].y - (float)hb[1]);
                    hb[2] = (_Float16)pb[i].z; lb[2] = (_Float16)(pb[i].z - (float)hb[2]);
                    hb[3] = (_Float16)pb[i].w; lb[3] = (_Float16)(pb[i].w - (float)hb[3]);
                    *(half4*)&Bh[row * GP + skq] = hb;
                    *(half4*)&Bl[row * GP + skq] = lb;
                }
            }
            __syncthreads();
            kk += 32;
            if (kb < 7) {
                #pragma unroll
                for (int i = 0; i < 2; ++i)
                    pa[i] = *(const float4*)&xb[(long)(r0 + srow + i * 32) * 2048 + kk + skq];
                if (!diag) {
                    #pragma unroll
                    for (int i = 0; i < 2; ++i)
                        pb[i] = *(const float4*)&xb[(long)(c0 + srow + i * 32) * 2048 + kk + skq];
                }
            }
            const _Float16* BhP = diag ? Ah : Bh;
            const _Float16* BlP = diag ? Al : Bl;
            #pragma unroll
            for (int ph = 0; ph < 3; ++ph) {
                const _Float16* As = (ph == 2) ? Al : Ah;
                const _Float16* Bs = (ph == 1) ? BlP : BhP;
                half8 af[2], bf[2];
                #pragma unroll
                for (int i = 0; i < 2; ++i) {
                    af[i] = *(const half8*)&As[aBase + i * 16 * GP];
                    bf[i] = *(const half8*)&Bs[bBase + i * 16 * GP];
                }
                #pragma unroll
                for (int i = 0; i < 2; ++i)
                    #pragma unroll
                    for (int j = 0; j < 2; ++j)
                        acc[i][j] = __builtin_amdgcn_mfma_f32_16x16x32_f16(af[i], bf[j], acc[i][j], 0, 0, 0);
            }
        }

        if (diag) {
            #pragma unroll
            for (int i = 0; i < 2; ++i) {
                rs[i] += __shfl_xor(rs[i], 1);
                rs[i] += __shfl_xor(rs[i], 2);
                rs[i] += __shfl_xor(rs[i], 4);
            }
            if ((t & 7) == 0) {
                #pragma unroll
                for (int i = 0; i < 2; ++i)
                    sxpart[ks * 2048 + b * 256 + r0 + srow + i * 32] = rs[i];
            }
        }

        float* D = Gpart + ((long)(ks * 8 + b) << 16);
        #pragma unroll
        for (int i = 0; i < 2; ++i)
            #pragma unroll
            for (int j = 0; j < 2; ++j) {
                const int row = r0 + wy * 32 + i * 16 + quad * 4;
                const int col = c0 + wx * 32 + j * 16 + mIn;
                #pragma unroll
                for (int r = 0; r < 4; ++r)
                    D[(row + r) * 256 + col] = acc[i][j][r];
                if (!diag)
                    *(float4*)&D[(long)col * 256 + row] =
                        make_float4(acc[i][j][0], acc[i][j][1], acc[i][j][2], acc[i][j][3]);
            }
    } else if (blk < 16) {
        float* ldsA = (float*)smem;
        float* ldsB = ldsA + 16 * 68;
        const int tile = blk;
        const int r0 = (tile >> 2) * 64, j0 = (tile & 3) * 64;
        const int tx = t & 15, ty = t >> 4;
        float acc[4][4] = {};
        for (int kk = 0; kk < 256; kk += 16) {
            *(float4*)&ldsA[ty * 68 + tx * 4] = *(const float4*)&Wq[(long)(kk + ty) * 256 + r0 + tx * 4];
            *(float4*)&ldsB[ty * 68 + tx * 4] = *(const float4*)&Wk[(long)(kk + ty) * 256 + j0 + tx * 4];
            __syncthreads();
            #pragma unroll
            for (int k = 0; k < 16; ++k) {
                const float4 av4 = *(const float4*)&ldsA[k * 68 + ty * 4];
                const float4 bv4 = *(const float4*)&ldsB[k * 68 + tx * 4];
                const float ar[4] = {av4.x, av4.y, av4.z, av4.w};
                const float br[4] = {bv4.x, bv4.y, bv4.z, bv4.w};
                #pragma unroll
                for (int i = 0; i < 4; ++i)
                    #pragma unroll
                    for (int j = 0; j < 4; ++j)
                        acc[i][j] = fmaf(ar[i], br[j], acc[i][j]);
            }
            __syncthreads();
        }
        #pragma unroll
        for (int i = 0; i < 4; ++i)
            *(float4*)&W3[(long)(r0 + ty * 4 + i) * 256 + j0 + tx * 4] =
                make_float4(acc[i][0], acc[i][1], acc[i][2], acc[i][3]);
    } else {                                   // blk == 16
        float* sbq = (float*)smem;
        float* sbk = sbq + 256;
        float* red = sbk + 256;
        if (t == 0) S[0] = 0.0f;
        sbq[t] = bq[t]; sbk[t] = bk[t];
        __syncthreads();
        float u = 0.0f, w = 0.0f;
        #pragma unroll 8
        for (int c = 0; c < 256; ++c) {
            u = fmaf(Wk[(long)c * 256 + t], sbq[c], u);   // coalesced columns
            w = fmaf(Wq[(long)c * 256 + t], sbk[c], w);
        }
        u2[t] = u; w1[t] = w;
        red[t] = sbq[t] * sbk[t]; __syncthreads();
        for (int h = 128; h > 0; h >>= 1) { if (t < h) red[t] += red[t + h]; __syncthreads(); }
        if (t == 0) s1[0] = red[0];
    }
}

// ---------------- K2: prep2 (0..7) | wvsx (8..15) | t1 32x32 (16..527) ----------------
__launch_bounds__(256)
__global__ void k2_kernel(const float* __restrict__ Wv, const float* __restrict__ Gpart,
                          const float* __restrict__ W3, const float* __restrict__ u2,
                          const float* __restrict__ w1, const float* __restrict__ s1p,
                          const float* __restrict__ sxpart, float* __restrict__ T1,
                          float* __restrict__ v2, float* __restrict__ s2,
                          float* __restrict__ wvsx, float* __restrict__ S) {
    __shared__ __align__(16) char smem[40960];
    const int blk = blockIdx.x, t = threadIdx.x;
    if (blk >= 16) {
        // T1_b = Wv * G_b, 32x32 tiles -> 512 blocks (2/CU). The 8 r0-blocks
        // sharing one (b,j0) Gpart panel are 64 apart -> same blk%8 -> same XCD.
        float* ldsA = (float*)smem;            // [32 k][34] transposed Wv panel
        float* ldsB = ldsA + 32 * 34;          // [32 k][36] reduced G panel
        const int gb = blk - 16;
        const int r0 = (gb >> 6) * 32;         // 0..224
        const int g  = gb & 63;
        const int b  = g >> 3;
        const int j0 = (g & 7) * 32;
        const int tx = t & 15, ty = t >> 4;
        const int ar = t >> 3, ak4 = (t & 7) * 4;      // A stage: row 0..31, k 0..28
        const int brow = t >> 3, bcol4 = (t & 7) * 4;  // B stage: k-row 0..31, j 0..28
        const float* Gb = Gpart + (long)b * 65536 + j0;
        float acc[2][2] = {};

        f4v pa, pg[8];
        pa = *(const f4v*)&Wv[(long)(r0 + ar) * 256 + ak4];
        #pragma unroll
        for (int ksl = 0; ksl < 8; ++ksl)
            pg[ksl] = *(const f4v*)&Gb[(long)ksl * 524288 + (long)brow * 256 + bcol4];

        for (int c = 0; c < 8; ++c) {
            const int kk = c * 32;
            ldsA[(ak4 + 0) * 34 + ar] = pa[0];
            ldsA[(ak4 + 1) * 34 + ar] = pa[1];
            ldsA[(ak4 + 2) * 34 + ar] = pa[2];
            ldsA[(ak4 + 3) * 34 + ar] = pa[3];
            {
                f4v bs = pg[0];
                #pragma unroll
                for (int ksl = 1; ksl < 8; ++ksl) bs += pg[ksl];
                *(f4v*)&ldsB[brow * 36 + bcol4] = bs;
            }
            __syncthreads();
            if (c < 7) {                       // issue next chunk's loads; FMA hides latency
                const int kn = kk + 32;
                pa = *(const f4v*)&Wv[(long)(r0 + ar) * 256 + kn + ak4];
                #pragma unroll
                for (int ksl = 0; ksl < 8; ++ksl)
                    pg[ksl] = *(const f4v*)&Gb[(long)ksl * 524288 + (long)(kn + brow) * 256 + bcol4];
            }
            #pragma unroll
            for (int k = 0; k < 32; ++k) {
                const float2 av2 = *(const float2*)&ldsA[k * 34 + ty * 2];
                const float2 bv2 = *(const float2*)&ldsB[k * 36 + tx * 2];
                acc[0][0] = fmaf(av2.x, bv2.x, acc[0][0]);
                acc[0][1] = fmaf(av2.x, bv2.y, acc[0][1]);
                acc[1][0] = fmaf(av2.y, bv2.x, acc[1][0]);
                acc[1][1] = fmaf(av2.y, bv2.y, acc[1][1]);
            }
            __syncthreads();
        }
        float* D = T1 + (long)b * 65536;
        #pragma unroll
        for (int i = 0; i < 2; ++i)
            *(float2*)&D[(long)(r0 + ty * 2 + i) * 256 + j0 + tx * 2] =
                make_float2(acc[i][0], acc[i][1]);
    } else if (blk < 8) {
        float* ssx = (float*)smem;
        float* red = ssx + 256;
        const int b = blk, j = t;
        float sxv = 0.0f;
        #pragma unroll
        for (int ks = 0; ks < 8; ++ks) sxv += sxpart[ks * 2048 + b * 256 + j];
        ssx[j] = sxv;
        __syncthreads();
        float vr = 0.0f;
        #pragma unroll 8
        for (int c = 0; c < 256; ++c) vr = fmaf(W3[(long)c * 256 + j], ssx[c], vr); // coalesced
        const float v2j = vr + 2048.0f * u2[j];
        v2[b * 256 + j] = v2j;
        red[j] = v2j * sxv; __syncthreads();
        for (int h = 128; h > 0; h >>= 1) { if (j < h) red[j] += red[j + h]; __syncthreads(); }
        const float sd1 = red[0];
        __syncthreads();
        red[j] = sxv * w1[j]; __syncthreads();
        for (int h = 128; h > 0; h >>= 1) { if (j < h) red[j] += red[j + h]; __syncthreads(); }
        if (j == 0) {
            const float s2v = red[0] + 2048.0f * s1p[0];
            s2[b] = s2v;
            atomicAdd(S, sd1 + 2048.0f * s2v);
        }
    } else {                                   // blk 8..15: wvsx
        float* wtile = (float*)smem;           // 32 x 256
        float* sxs = wtile + 8192;             // 2048
        const int r0w = (blk - 8) * 32;
        #pragma unroll
        for (int p = 0; p < 8; ++p) {
            const int f = t + p * 256;
            const int row = f >> 6, c4 = f & 63;
            *(float4*)&wtile[row * 256 + c4 * 4] = *(const float4*)&Wv[(long)(r0w + row) * 256 + c4 * 4];
        }
        #pragma unroll
        for (int p = 0; p < 8; ++p) {
            const int f = t + p * 256;
            float s = 0.0f;
            #pragma unroll
            for (int ks = 0; ks < 8; ++ks) s += sxpart[ks * 2048 + f];
            sxs[f] = s;
        }
        __syncthreads();
        const int r = t >> 3, q = t & 7;       // 32 rows x 8 k-groups
        float acc[8] = {};
        for (int ci = 0; ci < 32; ++ci) {
            const float wv = wtile[r * 256 + q * 32 + ci];
            #pragma unroll
            for (int b = 0; b < 8; ++b) acc[b] = fmaf(wv, sxs[b * 256 + q * 32 + ci], acc[b]);
        }
        #pragma unroll
        for (int b = 0; b < 8; ++b) {
            acc[b] += __shfl_xor(acc[b], 1);
            acc[b] += __shfl_xor(acc[b], 2);
            acc[b] += __shfl_xor(acc[b], 4);
        }
        if (q == 0) {
            #pragma unroll
            for (int b = 0; b < 8; ++b) wvsx[b * 256 + r0w + r] = acc[b];
        }
    }
}

// ---------------- K3: Ap = T1 W3 + wvsx(x)u2 + bv(x)v2 -> f16 hi/lo; cvec fold ----------------
// 32x32 tiles, grid (8,8,8) = 512 blocks (2/CU) + reg prefetch.
__launch_bounds__(256)
__global__ void ap_kernel(const float* __restrict__ T1, const float* __restrict__ W3,
                          const float* __restrict__ wvsx, const float* __restrict__ u2,
                          const float* __restrict__ bv, const float* __restrict__ v2,
                          const float* __restrict__ w1, const float* __restrict__ s1p,
                          const float* __restrict__ s2, _Float16* __restrict__ Aph,
                          _Float16* __restrict__ Apl, float* __restrict__ cvec) {
    __shared__ __align__(16) float ldsA[32 * 34];   // [32 k][34] transposed T1 panel
    __shared__ __align__(16) float ldsB[32 * 36];   // [32 k][36] W3 panel
    __shared__ float sw1[256];
    const int b = blockIdx.z;
    const int r0 = blockIdx.y * 32, j0 = blockIdx.x * 32;
    const float* A = T1 + (long)b * 65536;
    const int t = threadIdx.x, tx = t & 15, ty = t >> 4;
    const int ar = t >> 3, ak4 = (t & 7) * 4;
    const int brow = t >> 3, bcol4 = (t & 7) * 4;
    sw1[t] = w1[t];
    float acc[2][2] = {};
    float dot[2] = {};

    f4v pa, pb;
    pa = *(const f4v*)&A[(long)(r0 + ar) * 256 + ak4];
    pb = *(const f4v*)&W3[(long)brow * 256 + j0 + bcol4];

    for (int c = 0; c < 8; ++c) {
        const int kk = c * 32;
        ldsA[(ak4 + 0) * 34 + ar] = pa[0];
        ldsA[(ak4 + 1) * 34 + ar] = pa[1];
        ldsA[(ak4 + 2) * 34 + ar] = pa[2];
        ldsA[(ak4 + 3) * 34 + ar] = pa[3];
        *(f4v*)&ldsB[brow * 36 + bcol4] = pb;
        __syncthreads();
        if (c < 7) {                            // prefetch next chunk under FMA
            const int kn = kk + 32;
            pa = *(const f4v*)&A[(long)(r0 + ar) * 256 + kn + ak4];
            pb = *(const f4v*)&W3[(long)(kn + brow) * 256 + j0 + bcol4];
        }
        #pragma unroll
        for (int k = 0; k < 32; ++k) {
            const float2 av2 = *(const float2*)&ldsA[k * 34 + ty * 2];
            const float2 bv2 = *(const float2*)&ldsB[k * 36 + tx * 2];
            const float wk = sw1[kk + k];
            dot[0] = fmaf(av2.x, wk, dot[0]);
            dot[1] = fmaf(av2.y, wk, dot[1]);
            acc[0][0] = fmaf(av2.x, bv2.x, acc[0][0]);
            acc[0][1] = fmaf(av2.x, bv2.y, acc[0][1]);
            acc[1][0] = fmaf(av2.y, bv2.x, acc[1][0]);
            acc[1][1] = fmaf(av2.y, bv2.y, acc[1][1]);
        }
        __syncthreads();
    }
    #pragma unroll
    for (int i = 0; i < 2; ++i) {
        const int r = r0 + ty * 2 + i;
        const float e1 = wvsx[b * 256 + r], e3 = bv[r];
        half2v hv, lv;
        #pragma unroll
        for (int j = 0; j < 2; ++j) {
            const int col = j0 + tx * 2 + j;
            const float val = acc[i][j] + e1 * u2[col] + e3 * v2[b * 256 + col];
            hv[j] = (_Float16)val;
            lv[j] = (_Float16)(val - (float)hv[j]);
        }
        const long o = (long)b * 65536 + (long)r * 256 + j0 + tx * 2;
        *(half2v*)&Aph[o] = hv;
        *(half2v*)&Apl[o] = lv;
        if (j0 == 0 && tx == 0)
            cvec[b * 256 + r] = dot[i] + e1 * s1p[0] + e3 * s2[b];
    }
}

// ---------------- K4: out = (Ap x + cvec 1^T) / S ; 64x64 tiles, grid (32,4,8) ----------------
__launch_bounds__(256)
__global__ void gemmF_mfma(const _Float16* __restrict__ Aph, const _Float16* __restrict__ Apl,
                           const float* __restrict__ x, const float* __restrict__ Sptr,
                           const float* __restrict__ cvec, float* __restrict__ out) {
    __shared__ __align__(16) _Float16 Ah[64 * GP];
    __shared__ __align__(16) _Float16 Al[64 * GP];
    __shared__ __align__(16) _Float16 Bh[64 * GPB];
    __shared__ __align__(16) _Float16 Bl[64 * GPB];
    __shared__ __align__(16) float xt[32 * 68];

    const int n0 = blockIdx.x * 64;
    const int c0 = blockIdx.y * 64;
    const int b = blockIdx.z;
    const _Float16* Asrc_h = Aph + (long)b * 65536;
    const _Float16* Asrc_l = Apl + (long)b * 65536;
    const float* xb = x + (long)b * 524288;

    const int t = threadIdx.x;
    const int lane = t & 63, wave = t >> 6;
    const int wy = wave >> 1, wx = wave & 1;
    const int mIn = lane & 15, quad = lane >> 4;

    f4v acc[2][2] = {};
    const int aBase = (wy * 32 + mIn) * GP + quad * 8;
    const int bBase = (wx * 32 + mIn) * GPB + quad * 8;
    const int cn = t & 63;           // converter: n index (0..63)
    const int ck = (t >> 6) * 8;     // converter: k group base (0,8,16,24)

    const int arow = t >> 2, ako = (t & 3) << 3;   // A stage: 64 rows x 32 k halves
    int xk[2], xn[2];
    #pragma unroll
    for (int p = 0; p < 2; ++p) { const int f = t + p * 256; xk[p] = f >> 4; xn[p] = f & 15; }

    uint4 pah, pal; f4v px[2];
    pah = *(const uint4*)&Asrc_h[(long)(c0 + arow) * 256 + ako];
    pal = *(const uint4*)&Asrc_l[(long)(c0 + arow) * 256 + ako];
    #pragma unroll
    for (int p = 0; p < 2; ++p)
        px[p] = *(const f4v*)&xb[(long)xk[p] * 2048 + n0 + xn[p] * 4];

    for (int kk = 0; kk < 256; kk += 32) {
        *(uint4*)&Ah[arow * GP + ako] = pah;
        *(uint4*)&Al[arow * GP + ako] = pal;
        #pragma unroll
        for (int p = 0; p < 2; ++p)
            *(f4v*)&xt[xk[p] * 68 + xn[p] * 4] = px[p];
        __syncthreads();
        {
            _Float16 hs[8], ls[8];
            #pragma unroll
            for (int k = 0; k < 8; ++k) {
                const float v = xt[(ck + k) * 68 + cn];        // stride-1 lanes: 2-way (free)
                hs[k] = (_Float16)v;
                ls[k] = (_Float16)(v - (float)hs[k]);
            }
            #pragma unroll
            for (int k2 = 0; k2 < 4; ++k2) {
                half2v h2; h2[0] = hs[2 * k2]; h2[1] = hs[2 * k2 + 1];
                half2v l2; l2[0] = ls[2 * k2]; l2[1] = ls[2 * k2 + 1];
                *(half2v*)&Bh[cn * GPB + ck + 2 * k2] = h2;    // 18-dword stride: 2-way (free)
                *(half2v*)&Bl[cn * GPB + ck + 2 * k2] = l2;
            }
        }
        __syncthreads();
        if (kk < 224) {                         // prefetch next tile under MFMA phases
            const int kn = kk + 32;
            pah = *(const uint4*)&Asrc_h[(long)(c0 + arow) * 256 + kn + ako];
            pal = *(const uint4*)&Asrc_l[(long)(c0 + arow) * 256 + kn + ako];
            #pragma unroll
            for (int p = 0; p < 2; ++p)
                px[p] = *(const f4v*)&xb[(long)(kn + xk[p]) * 2048 + n0 + xn[p] * 4];
        }
        #pragma unroll
        for (int ph = 0; ph < 3; ++ph) {
            const _Float16* As = (ph == 2) ? Al : Ah;
            const _Float16* Bs = (ph == 1) ? Bl : Bh;
            half8 af[2], bf[2];
            #pragma unroll
            for (int i = 0; i < 2; ++i)
                af[i] = *(const half8*)&As[aBase + i * 16 * GP];
            #pragma unroll
            for (int j = 0; j < 2; ++j) {
                const half4 b0 = *(const half4*)&Bs[bBase + j * 16 * GPB];
                const half4 b1 = *(const half4*)&Bs[bBase + j * 16 * GPB + 4];
                bf[j] = __builtin_shufflevector(b0, b1, 0, 1, 2, 3, 4, 5, 6, 7);
            }
            #pragma unroll
            for (int i = 0; i < 2; ++i)
                #pragma unroll
                for (int j = 0; j < 2; ++j)
                    acc[i][j] = __builtin_amdgcn_mfma_f32_16x16x32_f16(af[i], bf[j], acc[i][j], 0, 0, 0);
        }
        __syncthreads();
    }

    const float invS = 1.0f / Sptr[0];
    float* ob = out + (long)b * 524288;
    const float* cv = cvec + b * 256;
    #pragma unroll
    for (int i = 0; i < 2; ++i)
        #pragma unroll
        for (int r = 0; r < 4; ++r) {
            const int row = c0 + wy * 32 + i * 16 + quad * 4 + r;
            const float c = cv[row];
            #pragma unroll
            for (int j = 0; j < 2; ++j) {
                const int col = n0 + wx * 32 + j * 16 + mIn;
                ob[(long)row * 2048 + col] = (acc[i][j][r] + c) * invS;
            }
        }
}

extern "C" void kernel_launch(void* const* d_in, const int* in_sizes, int n_in,
                              void* d_out, int out_size, void* d_ws, size_t ws_size,
                              hipStream_t stream) {
    const float* x  = (const float*)d_in[0];
    const float* Wq = (const float*)d_in[1];
    const float* bq = (const float*)d_in[2];
    const float* Wk = (const float*)d_in[3];
    const float* bk = (const float*)d_in[4];
    const float* Wv = (const float*)d_in[5];
    const float* bv = (const float*)d_in[6];
    float* out = (float*)d_out;
    float* ws  = (float*)d_ws;

    float* T1     = ws;                  // 524288
    float* W3     = ws + 524288;         // 65536
    float* sxpart = ws + 589824;         // 8*2048
    float* wvsx   = ws + 606208;         // 2048
    float* v2     = ws + 608256;         // 2048
    float* cvec   = ws + 610304;         // 2048
    float* s2     = ws + 612352;         // 8
    float* u2     = ws + 612360;         // 256
    float* w1     = ws + 612616;         // 256
    float* s1     = ws + 612872;         // 1
    float* S      = ws + 612873;         // 1
    float* Gpart  = ws + 612880;         // 8*8*65536 = 4194304 (16 MB)
    _Float16* Aph = (_Float16*)(ws + 4807184);   // 524288 halves
    _Float16* Apl = Aph + 524288;                // total ws ~21 MB

    k1_kernel<<<dim3(657), 256, 0, stream>>>(x, Wq, Wk, bq, bk, sxpart, W3, u2, w1, s1, S, Gpart);
    k2_kernel<<<dim3(528), 256, 0, stream>>>(Wv, Gpart, W3, u2, w1, s1, sxpart, T1, v2, s2, wvsx, S);
    ap_kernel<<<dim3(8, 8, 8), 256, 0, stream>>>(T1, W3, wvsx, u2, bv, v2, w1, s1, s2, Aph, Apl, cvec);
    gemmF_mfma<<<dim3(32, 4, 8), 256, 0, stream>>>(Aph, Apl, x, S, cvec, out);
}